// Round 3
// baseline (605.045 us; speedup 1.0000x reference)
//
#include <hip/hip_runtime.h>
#include <math.h>

// TrajDecoder on MI355X (gfx950).  Round 3: weight-stream bandwidth fix.
//   Diagnosis R1/R2: all pipes idle (MFMA 21%, VALU 13%, HBM 7%) -> the 4GB
//   w1/w2 re-fetch stream (16KB chunk x 1024 row-blocks x 4 heads) saturated
//   Infinity Cache (~6.7 TB/s).  Fix: (a) 128 rows/block (8 waves) halves the
//   stream to 2GB; (b) head->XCD pinning (head = (bid&7)>>1) makes the per-XCD
//   weight working set 4MB = L2 size, so re-fetches hit L2.
//   Structure otherwise identical: A-fragments in regs (16 rows/wave), B via
//   2-buffer LDS + global_load_lds, v_mfma_f32_16x16x32_f16, fused head GEMM,
//   deterministic 2-stage loss reduction.

#define KROWS 65536
#define DH 512

typedef _Float16 f16;
typedef _Float16 half8 __attribute__((ext_vector_type(8)));
typedef float floatx4 __attribute__((ext_vector_type(4)));

#define WS_WF16   0
#define WS_W3F16  4194304
#define WS_PRED2D 4227072
#define WS_PART   5275648

__device__ __forceinline__ void glds16(const void* g, void* l) {
  __builtin_amdgcn_global_load_lds(
      (const __attribute__((address_space(1))) void*)g,
      (__attribute__((address_space(3))) void*)l, 16, 0, 0);
}

// ---------------------------------------------------------------------------
// Weight conversion. Chunk layout: block index ((m*2+layer)*32 + nc*4 + kc),
// 16 KiB each = [64 n][128 k] f16, byte offset inside block:
//   nl*256 + ((klocal*2) ^ ((nl&7)<<4))
// ---------------------------------------------------------------------------
__global__ __launch_bounds__(256) void convert_weights(
    const float* __restrict__ w1, const float* __restrict__ w2,
    const float* __restrict__ w3, f16* __restrict__ wf16, f16* __restrict__ w3f16)
{
  int idx = blockIdx.x * 256 + threadIdx.x;
  const int NW = 2 * 4 * DH * DH;  // 2097152
  if (idx < NW) {
    int which = idx >> 20;              // 0 = w1, 1 = w2
    int r = idx & ((1 << 20) - 1);
    int mm = r >> 18;                   // head
    int nk = r & ((1 << 18) - 1);
    int n = nk >> 9, k = nk & 511;
    float v = which ? w2[r] : w1[r];
    int nc = n >> 6, nl = n & 63, kc = k >> 7;
    int klb = (k & 127) * 2;
    size_t off = ((size_t)((mm * 2 + which) * 32 + nc * 4 + kc)) * 16384
               + (size_t)(nl * 256 + (klb ^ ((nl & 7) << 4)));
    *(f16*)((unsigned char*)wf16 + off) = (f16)v;
  } else {
    int j = idx - NW;
    if (j < 23 * DH) w3f16[j] = (f16)w3[j];
  }
}

// ---------------------------------------------------------------------------
// Fused 2-layer MLP + head projection.
// grid = 2048 blocks of 512 threads (8 waves, 128 rows/block).
// bid decode pins each head to a fixed pair of XCDs (assumes XCD = bid % 8).
// ---------------------------------------------------------------------------
__global__ __launch_bounds__(512) void fused_kernel(
    const float* __restrict__ hidden,
    const f16* __restrict__ wf16,
    const f16* __restrict__ w3f16,
    const float* __restrict__ b1g,
    const float* __restrict__ b2g,
    const float* __restrict__ b3g,
    float* __restrict__ dout,
    float* __restrict__ pred2d)
{
  const int bid  = blockIdx.x;
  const int rr   = bid & 7;
  const int m    = rr >> 1;                        // head, pinned to XCD pair
  const int row_tile = ((bid >> 3) << 1) | (rr & 1);  // 0..511
  const int tid  = threadIdx.x;
  const int wave = tid >> 6;
  const int lane = tid & 63;
  const int l15  = lane & 15;
  const int lg   = lane >> 4;
  const int r0   = row_tile * 128 + wave * 16;

  __shared__ __align__(16) unsigned char ldsB[2][16384];
  __shared__ __align__(16) unsigned char ldsT[8][2048];
  unsigned char* tb = ldsT[wave];

  half8 A1[16], A2[16];
  floatx4 acc[4];
  floatx4 acc3 = {0.f, 0.f, 0.f, 0.f};
  const floatx4 zf = {0.f, 0.f, 0.f, 0.f};
  const half8 hz = {(f16)0, (f16)0, (f16)0, (f16)0, (f16)0, (f16)0, (f16)0, (f16)0};

  // stage granule g (chunk c of layer) into ldsB[g&1]; each wave stages 2KB.
  auto stage = [&](int g) {
    const int layer = g >> 5, c = g & 31;
    const unsigned char* src = (const unsigned char*)wf16
        + ((size_t)((m * 2 + layer) * 32 + c)) * 16384
        + (size_t)(wave * 2048 + lane * 16);
    unsigned char* dst = &ldsB[g & 1][wave * 2048];
    glds16(src, dst);
    glds16(src + 1024, dst + 1024);
  };

  auto bfrag = [&](int buf, int s, int kk) -> half8 {
    int nl = 16 * s + l15;
    int kb = 64 * kk + 16 * lg;
    return *(const half8*)(&ldsB[buf][nl * 256 + (kb ^ ((nl & 7) << 4))]);
  };

  // transpose-buffer read: A-fragment of the freshly produced activation tile.
  auto tread = [&](int kk) -> half8 {
    int col0 = 32 * kk + 8 * lg;
    int s = col0 >> 4, c0 = col0 & 15;
    int j = l15 & 3, g2 = l15 >> 2;
    return *(const half8*)(&tb[(s * 4 + j) * 128 + (((g2 * 16 + c0) * 2) ^ (j << 4))]);
  };

  stage(0);

  // ---- A1 fragments: hidden rows r0..r0+15, fp32 -> f16, k = 32q + 8*lg + i ----
  {
    const float* rp = hidden + (size_t)(r0 + l15) * DH + lg * 8;
#pragma unroll
    for (int q = 0; q < 16; ++q) {
      floatx4 u0 = *(const floatx4*)(rp + q * 32);
      floatx4 u1 = *(const floatx4*)(rp + q * 32 + 4);
      half8 a;
      a[0] = (f16)u0[0]; a[1] = (f16)u0[1]; a[2] = (f16)u0[2]; a[3] = (f16)u0[3];
      a[4] = (f16)u1[0]; a[5] = (f16)u1[1]; a[6] = (f16)u1[2]; a[7] = (f16)u1[3];
      A1[q] = a;
    }
  }

  const int base_m = (m == 0) ? 0 : (m == 1) ? 1 : (m == 2) ? 7 : 11;
  const int cnt_m  = (m == 0) ? 1 : (m == 1) ? 6 : (m == 2) ? 4 : 12;
  const bool ovalid = l15 < cnt_m;
  const f16* w3row = w3f16 + (size_t)(base_m + (ovalid ? l15 : 0)) * DH;

  __syncthreads();  // stage(0) visible to all waves

  // ================= layer 1: h1 = relu(x @ w1^T + b1) =================
#pragma unroll
  for (int nc = 0; nc < 8; ++nc) {
    acc[0] = zf; acc[1] = zf; acc[2] = zf; acc[3] = zf;
    float bs0 = 0.f, bs1 = 0.f, bs2 = 0.f, bs3 = 0.f;
#pragma unroll
    for (int kc = 0; kc < 4; ++kc) {
      const int g = nc * 4 + kc;
      if (g + 1 < 64) stage(g + 1);
      if (kc == 0) {
        bs0 = b1g[m * DH + 64 * nc + l15];
        bs1 = b1g[m * DH + 64 * nc + 16 + l15];
        bs2 = b1g[m * DH + 64 * nc + 32 + l15];
        bs3 = b1g[m * DH + 64 * nc + 48 + l15];
      }
      const int buf = g & 1;
#pragma unroll
      for (int kk = 0; kk < 4; ++kk) {
#pragma unroll
        for (int s = 0; s < 4; ++s)
          acc[s] = __builtin_amdgcn_mfma_f32_16x16x32_f16(
              A1[kc * 4 + kk], bfrag(buf, s, kk), acc[s], 0, 0, 0);
      }
      if (kc == 3) {
        const float bsv[4] = {bs0, bs1, bs2, bs3};
#pragma unroll
        for (int s = 0; s < 4; ++s) {
#pragma unroll
          for (int j = 0; j < 4; ++j) {
            float h = fmaxf(acc[s][j] + bsv[s], 0.f);
            *(f16*)(&tb[(s * 4 + j) * 128 + ((lane * 2) ^ (j << 4))]) = (f16)h;
          }
        }
        A2[nc * 2 + 0] = tread(0);
        A2[nc * 2 + 1] = tread(1);
      }
      __syncthreads();
    }
  }

  // ================= layer 2 + fused head =================
#pragma unroll
  for (int nc = 0; nc < 8; ++nc) {
    acc[0] = zf; acc[1] = zf; acc[2] = zf; acc[3] = zf;
    float bs0 = 0.f, bs1 = 0.f, bs2 = 0.f, bs3 = 0.f;
    half8 wa = hz, wb = hz;
#pragma unroll
    for (int kc = 0; kc < 4; ++kc) {
      const int g = 32 + nc * 4 + kc;
      if (g + 1 < 64) stage(g + 1);
      if (kc == 0) {
        bs0 = b2g[m * DH + 64 * nc + l15];
        bs1 = b2g[m * DH + 64 * nc + 16 + l15];
        bs2 = b2g[m * DH + 64 * nc + 32 + l15];
        bs3 = b2g[m * DH + 64 * nc + 48 + l15];
        if (ovalid) {
          wa = *(const half8*)(w3row + 64 * nc + 8 * lg);
          wb = *(const half8*)(w3row + 64 * nc + 32 + 8 * lg);
        }
      }
      const int buf = g & 1;
#pragma unroll
      for (int kk = 0; kk < 4; ++kk) {
#pragma unroll
        for (int s = 0; s < 4; ++s)
          acc[s] = __builtin_amdgcn_mfma_f32_16x16x32_f16(
              A2[kc * 4 + kk], bfrag(buf, s, kk), acc[s], 0, 0, 0);
      }
      if (kc == 3) {
        const float bsv[4] = {bs0, bs1, bs2, bs3};
#pragma unroll
        for (int s = 0; s < 4; ++s) {
#pragma unroll
          for (int j = 0; j < 4; ++j) {
            float h = fmaxf(acc[s][j] + bsv[s], 0.f);
            *(f16*)(&tb[(s * 4 + j) * 128 + ((lane * 2) ^ (j << 4))]) = (f16)h;
          }
        }
        const half8 a3a = tread(0);
        const half8 a3b = tread(1);
        acc3 = __builtin_amdgcn_mfma_f32_16x16x32_f16(a3a, wa, acc3, 0, 0, 0);
        acc3 = __builtin_amdgcn_mfma_f32_16x16x32_f16(a3b, wb, acc3, 0, 0, 0);
      }
      __syncthreads();
    }
  }

  // ---- epilogue: write predictions (packed layout) ----
  if (ovalid) {
    const float bo = b3g[base_m + l15];
#pragma unroll
    for (int j = 0; j < 4; ++j) {
      const int row = r0 + 4 * lg + j;
      const float v = acc3[j] + bo;
      if (m == 0)      { if (l15 == 0) dout[row] = v; }
      else if (m == 1) { dout[KROWS + row * 18 + (l15 < 3 ? l15 : l15 + 6)] = v; }
      else if (m == 2) { pred2d[row * 4 + l15] = v; }
      else             { dout[KROWS + row * 18 + (l15 < 6 ? l15 + 3 : l15 + 6)] = v; }
    }
  }
}

// ---------------------------------------------------------------------------
// Loss math helpers (scalar fp32, matches jnp reference)
// ---------------------------------------------------------------------------
__device__ __forceinline__ void safe_norm3(float x, float y, float z, float* o) {
  float n = sqrtf(x * x + y * y + z * z);
  if (n > 1e-6f) { o[0] = x / n; o[1] = y / n; o[2] = z / n; }
  else           { o[0] = 1.f;   o[1] = 0.f;   o[2] = 0.f; }
}

__device__ __forceinline__ void rot6d(const float* x, float* R) {
  float a1[3]; safe_norm3(x[0], x[1], x[2], a1);
  float d = a1[0] * x[3] + a1[1] * x[4] + a1[2] * x[5];
  float b2[3]; safe_norm3(x[3] - d * a1[0], x[4] - d * a1[1], x[5] - d * a1[2], b2);
  float a3[3];
  safe_norm3(a1[1] * b2[2] - a1[2] * b2[1],
             a1[2] * b2[0] - a1[0] * b2[2],
             a1[0] * b2[1] - a1[1] * b2[0], a3);
  float bb[3];
  safe_norm3(a3[1] * a1[2] - a3[2] * a1[1],
             a3[2] * a1[0] - a3[0] * a1[2],
             a3[0] * a1[1] - a3[1] * a1[0], bb);
  R[0] = a1[0]; R[1] = a1[1]; R[2] = a1[2];
  R[3] = bb[0]; R[4] = bb[1]; R[5] = bb[2];
  R[6] = a3[0]; R[7] = a3[1]; R[8] = a3[2];
}

__device__ __forceinline__ float geo_angle(const float* P, const float* G) {
  float M[9];
#pragma unroll
  for (int i = 0; i < 3; ++i)
#pragma unroll
    for (int l = 0; l < 3; ++l)
      M[i * 3 + l] = G[0 + i] * P[0 + l] + G[3 + i] * P[3 + l] + G[6 + i] * P[6 + l];
  float tr = M[0] + M[4] + M[8];
  float c = fminf(fmaxf((tr - 1.f) * 0.5f, -1.f + 1e-6f), 1.f - 1e-6f);
  float v0 = M[7] - M[5], v1 = M[2] - M[6], v2 = M[3] - M[1];
  float s = 0.5f * sqrtf(v0 * v0 + v1 * v1 + v2 * v2) + 1e-8f;
  return atan2f(s, c);
}

// accumulators: 0 t_num 1 t_den 2 tv_sum 3..6 n3T d3T n3F d3F
//               7..10 n2T d2T n2F d2F  11..14 nqT dqT nqF dqF  15 rot_num 16 rot_den
__global__ __launch_bounds__(256) void loss_partial(
    const float* __restrict__ gt, const float* __restrict__ dout,
    const float* __restrict__ pred2d, float* __restrict__ partials)
{
  const int r = blockIdx.x * 256 + threadIdx.x;
  const float* g  = gt + (size_t)r * 23;
  const float* pk = dout + KROWS + (size_t)r * 18;
  float a[17];

  const float pt = dout[r];
  const float tg = g[0];
  const float tv = (tg != -1000.f) ? 1.f : 0.f;
  const float dt = fabsf(pt - tg);
  a[0] = ((dt < 3.f) ? (0.5f * dt * dt / 3.f) : (dt - 1.5f)) * tv;
  a[1] = tv;
  a[2] = tv;
  const float wt = expf(-0.5f * (dt / 3.f) * (dt / 3.f)) * tv;  // time-valid branch weight

  float n3T = 0.f, d3T = 0.f, n3F = 0.f, d3F = 0.f;
#pragma unroll
  for (int j = 0; j < 6; ++j) {
    const float p = pk[j < 3 ? j : j + 6];
    const float q = g[1 + j];
    const float val = (q != -1000.f) ? 1.f : 0.f;
    const float d = fabsf(p - q);
    const float l = (d < 0.07f) ? (0.5f * d * d / 0.07f) : (d - 0.035f);
    n3T += l * val * wt; d3T += val * wt; n3F += l * val; d3F += val;
  }
  a[3] = n3T; a[4] = d3T; a[5] = n3F; a[6] = d3F;

  float n2T = 0.f, d2T = 0.f, n2F = 0.f, d2F = 0.f;
#pragma unroll
  for (int j = 0; j < 4; ++j) {
    const float p = pred2d[(size_t)r * 4 + j];
    const float q = g[7 + j];
    const float val = (q != -1000.f) ? 1.f : 0.f;
    const float d = fabsf(p / 1408.f - q / 1408.f);
    const float l = (d < 0.02f) ? (0.5f * d * d / 0.02f) : (d - 0.01f);
    n2T += l * val * wt; d2T += val * wt; n2F += l * val; d2F += val;
  }
  a[7] = n2T; a[8] = d2T; a[9] = n2F; a[10] = d2F;

  float qp[12];
#pragma unroll
  for (int j = 0; j < 12; ++j) qp[j] = pk[j < 6 ? j + 3 : j + 6];
  float nqT = 0.f, dqT = 0.f, nqF = 0.f, dqF = 0.f;
#pragma unroll
  for (int j = 0; j < 12; ++j) {
    const float q = g[11 + j];
    const float val = (q != -1000.f) ? 1.f : 0.f;
    const float d = fabsf(qp[j] - q);
    const float l = (d < 0.2f) ? (0.5f * d * d / 0.2f) : (d - 0.1f);
    nqT += l * val * wt; dqT += val * wt; nqF += l * val; dqF += val;
  }
  a[11] = nqT; a[12] = dqT; a[13] = nqF; a[14] = dqF;

  bool Lv = true, Rv = true;
#pragma unroll
  for (int j = 0; j < 6; ++j) {
    if (g[11 + j] == -1000.f) Lv = false;
    if (g[17 + j] == -1000.f) Rv = false;
  }
  const float safe6[6] = {1.f, 0.f, 0.f, 0.f, 1.f, 0.f};
  float Lt[6], Rt[6];
#pragma unroll
  for (int j = 0; j < 6; ++j) {
    Lt[j] = Lv ? g[11 + j] : safe6[j];
    Rt[j] = Rv ? g[17 + j] : safe6[j];
  }
  float Rp[9], Rg[9];
  rot6d(qp, Rp);     rot6d(Lt, Rg);
  const float angL = geo_angle(Rp, Rg);
  rot6d(qp + 6, Rp); rot6d(Rt, Rg);
  const float angR = geo_angle(Rp, Rg);
  a[15] = (Lv ? angL : 0.f) + (Rv ? angR : 0.f);
  a[16] = (Lv ? 1.f : 0.f) + (Rv ? 1.f : 0.f);

  // block reduction (deterministic)
#pragma unroll
  for (int i = 0; i < 17; ++i) {
    float v = a[i];
#pragma unroll
    for (int off = 32; off > 0; off >>= 1) v += __shfl_down(v, off, 64);
    a[i] = v;
  }
  __shared__ float red[4][17];
  if ((threadIdx.x & 63) == 0) {
    const int w = threadIdx.x >> 6;
#pragma unroll
    for (int i = 0; i < 17; ++i) red[w][i] = a[i];
  }
  __syncthreads();
  if (threadIdx.x < 17)
    partials[blockIdx.x * 20 + threadIdx.x] =
        red[0][threadIdx.x] + red[1][threadIdx.x] + red[2][threadIdx.x] + red[3][threadIdx.x];
}

__global__ void loss_final(const float* __restrict__ partials, float* __restrict__ dout)
{
  __shared__ float s[17];
  const int i = threadIdx.x;
  if (i < 17) {
    float v = 0.f;
    for (int b = 0; b < 256; ++b) v += partials[b * 20 + i];
    s[i] = v;
  }
  __syncthreads();
  if (i == 0) {
    const bool flag = s[2] > 0.f;
    const float time_loss = s[0] / fmaxf(s[1], 1.f);
    const float l3 = flag ? s[3] / fmaxf(s[4], 1.f) : s[5] / fmaxf(s[6], 1.f);
    const float l2 = flag ? s[7] / fmaxf(s[8], 1.f) : s[9] / fmaxf(s[10], 1.f);
    const float lq = flag ? s[11] / fmaxf(s[12], 1.f) : s[13] / fmaxf(s[14], 1.f);
    const float rot = 0.15f * (s[15] / fmaxf(s[16], 1e-8f));
    dout[19 * KROWS] = time_loss + 2.f * l3 + 0.5f * l2 + 0.5f * lq + rot;
  }
}

// ---------------------------------------------------------------------------
extern "C" void kernel_launch(void* const* d_in, const int* in_sizes, int n_in,
                              void* d_out, int out_size, void* d_ws, size_t ws_size,
                              hipStream_t stream) {
  (void)in_sizes; (void)n_in; (void)out_size; (void)ws_size;
  const float* hidden = (const float*)d_in[0];
  const float* gt     = (const float*)d_in[1];
  const float* w1     = (const float*)d_in[2];
  const float* b1     = (const float*)d_in[3];
  const float* w2     = (const float*)d_in[4];
  const float* b2     = (const float*)d_in[5];
  const float* w3     = (const float*)d_in[6];
  const float* b3     = (const float*)d_in[7];
  float* dout = (float*)d_out;

  unsigned char* ws = (unsigned char*)d_ws;
  f16*   wf16     = (f16*)(ws + WS_WF16);
  f16*   w3f16    = (f16*)(ws + WS_W3F16);
  float* pred2d   = (float*)(ws + WS_PRED2D);
  float* partials = (float*)(ws + WS_PART);

  convert_weights<<<8238, 256, 0, stream>>>(w1, w2, w3, wf16, w3f16);
  fused_kernel<<<2048, 512, 0, stream>>>(hidden, wf16, w3f16, b1, b2, b3, dout, pred2d);
  loss_partial<<<256, 256, 0, stream>>>(gt, dout, pred2d, partials);
  loss_final<<<1, 64, 0, stream>>>(partials, dout);
}

// Round 4
// 463.436 us; speedup vs baseline: 1.3056x; 1.3056x over previous
//
#include <hip/hip_runtime.h>
#include <math.h>

// TrajDecoder on MI355X (gfx950).  Round 4: raise FLOP per LDS-byte.
//   R1-R3 invariant: LDS port saturated by B-fragment re-reads (16 FLOP/byte,
//   16-row waves).  New structure: BM=128, 8 waves, wave tile 128x64
//   (43 FLOP/LDS-byte).  A (hidden chunk, then h1) streamed through swizzled
//   16KB LDS chunks; B-fragments read directly from global (frag-packed,
//   1KB-coalesced, L2-resident via head->XCD pinning); h1[128x512] f16 kept in
//   LDS so layer 2 + head GEMM run barrier-free.  LDS = 160KB dynamic.

#define KROWS 65536
#define DH 512

typedef _Float16 f16;
typedef _Float16 half8 __attribute__((ext_vector_type(8)));
typedef float floatx4 __attribute__((ext_vector_type(4)));

#define WS_WF16   0
#define WS_W3F16  4194304
#define WS_PRED2D 4227072
#define WS_PART   5275648

// ---------------------------------------------------------------------------
// Weight conversion into fragment-packed layout:
//   region (m,l): 512KB at ml*262144 f16.  frag-block fb = nt*16 + kq (1KB):
//   lane(l15,lg) slot holds w[nt*16+l15][kq*32+lg*8 .. +8].
//   A wave's B-frag load = one dwordx4 at fb*1024 + lane*16 (coalesced 1KB).
// ---------------------------------------------------------------------------
__global__ __launch_bounds__(256) void convert_weights(
    const float* __restrict__ w1, const float* __restrict__ w2,
    const float* __restrict__ w3, f16* __restrict__ wf16, f16* __restrict__ w3f16)
{
  int t = blockIdx.x * 256 + threadIdx.x;
  if (t < 262144) {
    int ml = t >> 15;              // (m,l) 0..7
    int mm = ml >> 1, l = ml & 1;
    int r = t & 32767;
    int fb = r >> 6;               // nt*16+kq, 0..511
    int lane = r & 63;
    int nt = fb >> 4, kq = fb & 15;
    int n = nt * 16 + (lane & 15);
    int k = kq * 32 + (lane >> 4) * 8;
    const float* src = (l ? w2 : w1) + (size_t)mm * 262144 + n * 512 + k;
    floatx4 u0 = *(const floatx4*)(src);
    floatx4 u1 = *(const floatx4*)(src + 4);
    half8 h;
    h[0] = (f16)u0[0]; h[1] = (f16)u0[1]; h[2] = (f16)u0[2]; h[3] = (f16)u0[3];
    h[4] = (f16)u1[0]; h[5] = (f16)u1[1]; h[6] = (f16)u1[2]; h[7] = (f16)u1[3];
    *(half8*)(wf16 + (size_t)ml * 262144 + fb * 512 + lane * 8) = h;
  } else {
    int j = t - 262144;
    if (j < 23 * DH) w3f16[j] = (f16)w3[j];
  }
}

// ---------------------------------------------------------------------------
// Fused 2-layer MLP + head.  grid = 2048 blocks x 512 threads (8 waves).
// LDS: [0,128K) h1/h2 region as 8 chunks of [128r x 64c] f16 swizzled;
//      [128K,160K) hidden staging, 2 x 16KB chunks.
// Swizzle: value(row, c) at byte row*128 + (2c ^ ((row&7)<<4)).
// ---------------------------------------------------------------------------
extern __shared__ unsigned char smem[];

__global__ __launch_bounds__(512, 2) void fused_kernel(
    const float* __restrict__ hidden,
    const f16* __restrict__ wf16,
    const f16* __restrict__ w3f16,
    const float* __restrict__ b1g,
    const float* __restrict__ b2g,
    const float* __restrict__ b3g,
    float* __restrict__ dout,
    float* __restrict__ pred2d)
{
  const int bid = blockIdx.x;
  const int rr  = bid & 7;
  const int m   = rr >> 1;                          // head -> XCD pair
  const int row_tile = ((bid >> 3) << 1) | (rr & 1);
  const int r0  = row_tile * 128;
  const int tid = threadIdx.x;
  const int w   = tid >> 6;
  const int lane = tid & 63;
  const int l15 = lane & 15;
  const int lg  = lane >> 4;

  unsigned char* h1b = smem;             // 128KB: chunk c at c*16384
  unsigned char* stg = smem + 131072;    // 2 x 16KB

  const f16* wbase = wf16 + (size_t)(m * 2) * 262144;

  // staging coords (whole block stages one [128r x 64k] chunk)
  const int srow = tid >> 2;             // 0..127
  const int scg  = tid & 3;              // 16 f32 each
  const int ssw  = (srow & 7) << 4;
  const float* hrow = hidden + (size_t)(r0 + srow) * DH + scg * 16;

  floatx4 s0, s1, s2, s3;
  auto sload = [&](int kc) {
    const float* p = hrow + kc * 64;
    s0 = *(const floatx4*)(p);
    s1 = *(const floatx4*)(p + 4);
    s2 = *(const floatx4*)(p + 8);
    s3 = *(const floatx4*)(p + 12);
  };
  auto swrite = [&](int buf) {
    half8 p0, p1;
    p0[0] = (f16)s0[0]; p0[1] = (f16)s0[1]; p0[2] = (f16)s0[2]; p0[3] = (f16)s0[3];
    p0[4] = (f16)s1[0]; p0[5] = (f16)s1[1]; p0[6] = (f16)s1[2]; p0[7] = (f16)s1[3];
    p1[0] = (f16)s2[0]; p1[1] = (f16)s2[1]; p1[2] = (f16)s2[2]; p1[3] = (f16)s2[3];
    p1[4] = (f16)s3[0]; p1[5] = (f16)s3[1]; p1[6] = (f16)s3[2]; p1[7] = (f16)s3[3];
    unsigned char* base = stg + buf * 16384 + srow * 128;
    *(half8*)(base + ((scg * 32) ^ ssw))      = p0;
    *(half8*)(base + ((scg * 32 + 16) ^ ssw)) = p1;
  };

  // A-fragment read from a swizzled [128 x 64] chunk: rows mt*16+l15,
  // k-elems 32*kq + 8*lg .. +8.
  const int asw = (l15 & 7) << 4;
  auto aread = [&](const unsigned char* chunk, int mt, int kq) -> half8 {
    return *(const half8*)(chunk + (mt * 16 + l15) * 128 + ((kq * 64 + lg * 16) ^ asw));
  };

  // B-fragment (layer l, k-granule g=0..15, local n-tile nt) — global, coalesced.
  auto bload = [&](int l, int g, int nt) -> half8 {
    return *(const half8*)(wbase + (size_t)l * 262144
                           + (size_t)(((w * 4 + nt) * 16 + g) * 512) + lane * 8);
  };

  floatx4 acc[8][4];
  const floatx4 zf = {0.f, 0.f, 0.f, 0.f};
  const half8 hz = {(f16)0, (f16)0, (f16)0, (f16)0, (f16)0, (f16)0, (f16)0, (f16)0};

  // biases for this wave's 64 cols
  float bia[4], bib[4];
#pragma unroll
  for (int nt = 0; nt < 4; ++nt) {
    bia[nt] = b1g[m * DH + w * 64 + nt * 16 + l15];
    bib[nt] = b2g[m * DH + w * 64 + nt * 16 + l15];
  }

  // ---------------- layer 1 ----------------
  sload(0); swrite(0);
  __syncthreads();

  half8 bcur[4], bnxt[4];
#pragma unroll
  for (int nt = 0; nt < 4; ++nt) bcur[nt] = bload(0, 0, nt);
#pragma unroll
  for (int mt = 0; mt < 8; ++mt)
#pragma unroll
    for (int nt = 0; nt < 4; ++nt) acc[mt][nt] = zf;

#pragma unroll
  for (int g = 0; g < 16; ++g) {
    const int kc = g >> 1;
    if (g < 15) {
#pragma unroll
      for (int nt = 0; nt < 4; ++nt) bnxt[nt] = bload(0, g + 1, nt);
    }
    if ((g & 1) == 0 && kc < 7) sload(kc + 1);
    half8 a[8];
#pragma unroll
    for (int mt = 0; mt < 8; ++mt) a[mt] = aread(stg + (kc & 1) * 16384, mt, g & 1);
#pragma unroll
    for (int mt = 0; mt < 8; ++mt)
#pragma unroll
      for (int nt = 0; nt < 4; ++nt)
        acc[mt][nt] = __builtin_amdgcn_mfma_f32_16x16x32_f16(a[mt], bcur[nt], acc[mt][nt], 0, 0, 0);
    if ((g & 1) == 1 && kc < 7) {
      swrite((kc + 1) & 1);
      __syncthreads();
    }
    if (g < 15) {
#pragma unroll
      for (int nt = 0; nt < 4; ++nt) bcur[nt] = bnxt[nt];
    }
  }

  // prefetch layer-2 first B while writing h1
#pragma unroll
  for (int nt = 0; nt < 4; ++nt) bnxt[nt] = bload(1, 0, nt);

  // h1 epilogue: bias+relu -> wave's col chunk (chunk index w)
  {
    unsigned char* myc = h1b + w * 16384;
#pragma unroll
    for (int mt = 0; mt < 8; ++mt)
#pragma unroll
      for (int nt = 0; nt < 4; ++nt)
#pragma unroll
        for (int j = 0; j < 4; ++j) {
          float v = fmaxf(acc[mt][nt][j] + bia[nt], 0.f);
          int row = mt * 16 + 4 * lg + j;
          *(f16*)(myc + row * 128 + ((2 * (nt * 16 + l15)) ^ ((row & 7) << 4))) = (f16)v;
        }
  }
  __syncthreads();

  // ---------------- layer 2 (barrier-free) ----------------
#pragma unroll
  for (int nt = 0; nt < 4; ++nt) bcur[nt] = bnxt[nt];
#pragma unroll
  for (int mt = 0; mt < 8; ++mt)
#pragma unroll
    for (int nt = 0; nt < 4; ++nt) acc[mt][nt] = zf;

#pragma unroll
  for (int g = 0; g < 16; ++g) {
    if (g < 15) {
#pragma unroll
      for (int nt = 0; nt < 4; ++nt) bnxt[nt] = bload(1, g + 1, nt);
    }
    half8 a[8];
#pragma unroll
    for (int mt = 0; mt < 8; ++mt) a[mt] = aread(h1b + (g >> 1) * 16384, mt, g & 1);
#pragma unroll
    for (int mt = 0; mt < 8; ++mt)
#pragma unroll
      for (int nt = 0; nt < 4; ++nt)
        acc[mt][nt] = __builtin_amdgcn_mfma_f32_16x16x32_f16(a[mt], bcur[nt], acc[mt][nt], 0, 0, 0);
    if (g < 15) {
#pragma unroll
      for (int nt = 0; nt < 4; ++nt) bcur[nt] = bnxt[nt];
    }
  }

  __syncthreads();  // everyone done reading h1

  // h2 -> same col chunk (region reuse)
  {
    unsigned char* myc = h1b + w * 16384;
#pragma unroll
    for (int mt = 0; mt < 8; ++mt)
#pragma unroll
      for (int nt = 0; nt < 4; ++nt)
#pragma unroll
        for (int j = 0; j < 4; ++j) {
          float v = fmaxf(acc[mt][nt][j] + bib[nt], 0.f);
          int row = mt * 16 + 4 * lg + j;
          *(f16*)(myc + row * 128 + ((2 * (nt * 16 + l15)) ^ ((row & 7) << 4))) = (f16)v;
        }
  }
  __syncthreads();

  // ---------------- head GEMM: wave w -> rows 16w..16w+15 ----------------
  const int base_m = (m == 0) ? 0 : (m == 1) ? 1 : (m == 2) ? 7 : 11;
  const int cnt_m  = (m == 0) ? 1 : (m == 1) ? 6 : (m == 2) ? 4 : 12;
  const bool ovalid = l15 < cnt_m;
  const f16* w3row = w3f16 + (size_t)(base_m + (ovalid ? l15 : 0)) * DH;

  floatx4 acc3 = zf;
#pragma unroll
  for (int q = 0; q < 16; ++q) {
    half8 ah = aread(h1b + (q >> 1) * 16384, w, q & 1);
    half8 wv = ovalid ? *(const half8*)(w3row + q * 32 + lg * 8) : hz;
    acc3 = __builtin_amdgcn_mfma_f32_16x16x32_f16(ah, wv, acc3, 0, 0, 0);
  }

  if (ovalid) {
    const float bo = b3g[base_m + l15];
#pragma unroll
    for (int j = 0; j < 4; ++j) {
      const int row = r0 + w * 16 + 4 * lg + j;
      const float v = acc3[j] + bo;
      if (m == 0)      { if (l15 == 0) dout[row] = v; }
      else if (m == 1) { dout[KROWS + row * 18 + (l15 < 3 ? l15 : l15 + 6)] = v; }
      else if (m == 2) { pred2d[row * 4 + l15] = v; }
      else             { dout[KROWS + row * 18 + (l15 < 6 ? l15 + 3 : l15 + 6)] = v; }
    }
  }
}

// ---------------------------------------------------------------------------
// Loss math helpers (scalar fp32, matches jnp reference)
// ---------------------------------------------------------------------------
__device__ __forceinline__ void safe_norm3(float x, float y, float z, float* o) {
  float n = sqrtf(x * x + y * y + z * z);
  if (n > 1e-6f) { o[0] = x / n; o[1] = y / n; o[2] = z / n; }
  else           { o[0] = 1.f;   o[1] = 0.f;   o[2] = 0.f; }
}

__device__ __forceinline__ void rot6d(const float* x, float* R) {
  float a1[3]; safe_norm3(x[0], x[1], x[2], a1);
  float d = a1[0] * x[3] + a1[1] * x[4] + a1[2] * x[5];
  float b2[3]; safe_norm3(x[3] - d * a1[0], x[4] - d * a1[1], x[5] - d * a1[2], b2);
  float a3[3];
  safe_norm3(a1[1] * b2[2] - a1[2] * b2[1],
             a1[2] * b2[0] - a1[0] * b2[2],
             a1[0] * b2[1] - a1[1] * b2[0], a3);
  float bb[3];
  safe_norm3(a3[1] * a1[2] - a3[2] * a1[1],
             a3[2] * a1[0] - a3[0] * a1[2],
             a3[0] * a1[1] - a3[1] * a1[0], bb);
  R[0] = a1[0]; R[1] = a1[1]; R[2] = a1[2];
  R[3] = bb[0]; R[4] = bb[1]; R[5] = bb[2];
  R[6] = a3[0]; R[7] = a3[1]; R[8] = a3[2];
}

__device__ __forceinline__ float geo_angle(const float* P, const float* G) {
  float M[9];
#pragma unroll
  for (int i = 0; i < 3; ++i)
#pragma unroll
    for (int l = 0; l < 3; ++l)
      M[i * 3 + l] = G[0 + i] * P[0 + l] + G[3 + i] * P[3 + l] + G[6 + i] * P[6 + l];
  float tr = M[0] + M[4] + M[8];
  float c = fminf(fmaxf((tr - 1.f) * 0.5f, -1.f + 1e-6f), 1.f - 1e-6f);
  float v0 = M[7] - M[5], v1 = M[2] - M[6], v2 = M[3] - M[1];
  float s = 0.5f * sqrtf(v0 * v0 + v1 * v1 + v2 * v2) + 1e-8f;
  return atan2f(s, c);
}

// accumulators: 0 t_num 1 t_den 2 tv_sum 3..6 n3T d3T n3F d3F
//               7..10 n2T d2T n2F d2F  11..14 nqT dqT nqF dqF  15 rot_num 16 rot_den
__global__ __launch_bounds__(256) void loss_partial(
    const float* __restrict__ gt, const float* __restrict__ dout,
    const float* __restrict__ pred2d, float* __restrict__ partials)
{
  const int r = blockIdx.x * 256 + threadIdx.x;
  const float* g  = gt + (size_t)r * 23;
  const float* pk = dout + KROWS + (size_t)r * 18;
  float a[17];

  const float pt = dout[r];
  const float tg = g[0];
  const float tv = (tg != -1000.f) ? 1.f : 0.f;
  const float dt = fabsf(pt - tg);
  a[0] = ((dt < 3.f) ? (0.5f * dt * dt / 3.f) : (dt - 1.5f)) * tv;
  a[1] = tv;
  a[2] = tv;
  const float wt = expf(-0.5f * (dt / 3.f) * (dt / 3.f)) * tv;

  float n3T = 0.f, d3T = 0.f, n3F = 0.f, d3F = 0.f;
#pragma unroll
  for (int j = 0; j < 6; ++j) {
    const float p = pk[j < 3 ? j : j + 6];
    const float q = g[1 + j];
    const float val = (q != -1000.f) ? 1.f : 0.f;
    const float d = fabsf(p - q);
    const float l = (d < 0.07f) ? (0.5f * d * d / 0.07f) : (d - 0.035f);
    n3T += l * val * wt; d3T += val * wt; n3F += l * val; d3F += val;
  }
  a[3] = n3T; a[4] = d3T; a[5] = n3F; a[6] = d3F;

  float n2T = 0.f, d2T = 0.f, n2F = 0.f, d2F = 0.f;
#pragma unroll
  for (int j = 0; j < 4; ++j) {
    const float p = pred2d[(size_t)r * 4 + j];
    const float q = g[7 + j];
    const float val = (q != -1000.f) ? 1.f : 0.f;
    const float d = fabsf(p / 1408.f - q / 1408.f);
    const float l = (d < 0.02f) ? (0.5f * d * d / 0.02f) : (d - 0.01f);
    n2T += l * val * wt; d2T += val * wt; n2F += l * val; d2F += val;
  }
  a[7] = n2T; a[8] = d2T; a[9] = n2F; a[10] = d2F;

  float qp[12];
#pragma unroll
  for (int j = 0; j < 12; ++j) qp[j] = pk[j < 6 ? j + 3 : j + 6];
  float nqT = 0.f, dqT = 0.f, nqF = 0.f, dqF = 0.f;
#pragma unroll
  for (int j = 0; j < 12; ++j) {
    const float q = g[11 + j];
    const float val = (q != -1000.f) ? 1.f : 0.f;
    const float d = fabsf(qp[j] - q);
    const float l = (d < 0.2f) ? (0.5f * d * d / 0.2f) : (d - 0.1f);
    nqT += l * val * wt; dqT += val * wt; nqF += l * val; dqF += val;
  }
  a[11] = nqT; a[12] = dqT; a[13] = nqF; a[14] = dqF;

  bool Lv = true, Rv = true;
#pragma unroll
  for (int j = 0; j < 6; ++j) {
    if (g[11 + j] == -1000.f) Lv = false;
    if (g[17 + j] == -1000.f) Rv = false;
  }
  const float safe6[6] = {1.f, 0.f, 0.f, 0.f, 1.f, 0.f};
  float Lt[6], Rt[6];
#pragma unroll
  for (int j = 0; j < 6; ++j) {
    Lt[j] = Lv ? g[11 + j] : safe6[j];
    Rt[j] = Rv ? g[17 + j] : safe6[j];
  }
  float Rp[9], Rg[9];
  rot6d(qp, Rp);     rot6d(Lt, Rg);
  const float angL = geo_angle(Rp, Rg);
  rot6d(qp + 6, Rp); rot6d(Rt, Rg);
  const float angR = geo_angle(Rp, Rg);
  a[15] = (Lv ? angL : 0.f) + (Rv ? angR : 0.f);
  a[16] = (Lv ? 1.f : 0.f) + (Rv ? 1.f : 0.f);

#pragma unroll
  for (int i = 0; i < 17; ++i) {
    float v = a[i];
#pragma unroll
    for (int off = 32; off > 0; off >>= 1) v += __shfl_down(v, off, 64);
    a[i] = v;
  }
  __shared__ float red[4][17];
  if ((threadIdx.x & 63) == 0) {
    const int wv = threadIdx.x >> 6;
#pragma unroll
    for (int i = 0; i < 17; ++i) red[wv][i] = a[i];
  }
  __syncthreads();
  if (threadIdx.x < 17)
    partials[blockIdx.x * 20 + threadIdx.x] =
        red[0][threadIdx.x] + red[1][threadIdx.x] + red[2][threadIdx.x] + red[3][threadIdx.x];
}

__global__ void loss_final(const float* __restrict__ partials, float* __restrict__ dout)
{
  __shared__ float s[17];
  const int i = threadIdx.x;
  if (i < 17) {
    float v = 0.f;
    for (int b = 0; b < 256; ++b) v += partials[b * 20 + i];
    s[i] = v;
  }
  __syncthreads();
  if (i == 0) {
    const bool flag = s[2] > 0.f;
    const float time_loss = s[0] / fmaxf(s[1], 1.f);
    const float l3 = flag ? s[3] / fmaxf(s[4], 1.f) : s[5] / fmaxf(s[6], 1.f);
    const float l2 = flag ? s[7] / fmaxf(s[8], 1.f) : s[9] / fmaxf(s[10], 1.f);
    const float lq = flag ? s[11] / fmaxf(s[12], 1.f) : s[13] / fmaxf(s[14], 1.f);
    const float rot = 0.15f * (s[15] / fmaxf(s[16], 1e-8f));
    dout[19 * KROWS] = time_loss + 2.f * l3 + 0.5f * l2 + 0.5f * lq + rot;
  }
}

// ---------------------------------------------------------------------------
extern "C" void kernel_launch(void* const* d_in, const int* in_sizes, int n_in,
                              void* d_out, int out_size, void* d_ws, size_t ws_size,
                              hipStream_t stream) {
  (void)in_sizes; (void)n_in; (void)out_size; (void)ws_size;
  const float* hidden = (const float*)d_in[0];
  const float* gt     = (const float*)d_in[1];
  const float* w1     = (const float*)d_in[2];
  const float* b1     = (const float*)d_in[3];
  const float* w2     = (const float*)d_in[4];
  const float* b2     = (const float*)d_in[5];
  const float* w3     = (const float*)d_in[6];
  const float* b3     = (const float*)d_in[7];
  float* dout = (float*)d_out;

  unsigned char* ws = (unsigned char*)d_ws;
  f16*   wf16     = (f16*)(ws + WS_WF16);
  f16*   w3f16    = (f16*)(ws + WS_W3F16);
  float* pred2d   = (float*)(ws + WS_PRED2D);
  float* partials = (float*)(ws + WS_PART);

  static bool attr_done = false;
  if (!attr_done) {
    hipFuncSetAttribute(reinterpret_cast<const void*>(fused_kernel),
                        hipFuncAttributeMaxDynamicSharedMemorySize, 163840);
    attr_done = true;
  }

  convert_weights<<<1070, 256, 0, stream>>>(w1, w2, w3, wf16, w3f16);
  fused_kernel<<<2048, 512, 163840, stream>>>(hidden, wf16, w3f16, b1, b2, b3, dout, pred2d);
  loss_partial<<<256, 256, 0, stream>>>(gt, dout, pred2d, partials);
  loss_final<<<1, 64, 0, stream>>>(partials, dout);
}